// Round 16
// baseline (376.294 us; speedup 1.0000x reference)
//
#include <hip/hip_runtime.h>
#include <hip/hip_bf16.h>

#define N_TOK 32768
#define DIM 1024
#define OUTD 1024
#define NEXP 64

typedef __attribute__((ext_vector_type(4))) float f32x4;
typedef __attribute__((ext_vector_type(8))) short bf16x8;

__device__ __forceinline__ unsigned short f2bf(float f) {
    unsigned int u = __builtin_bit_cast(unsigned int, f);
    u += 0x7FFFu + ((u >> 16) & 1u);   // RNE
    return (unsigned short)(u >> 16);
}

__device__ __forceinline__ uint4 pack8(float4 a, float4 b) {
    uint4 p;
    p.x = (unsigned int)f2bf(a.x) | ((unsigned int)f2bf(a.y) << 16);
    p.y = (unsigned int)f2bf(a.z) | ((unsigned int)f2bf(a.w) << 16);
    p.z = (unsigned int)f2bf(b.x) | ((unsigned int)f2bf(b.y) << 16);
    p.w = (unsigned int)f2bf(b.z) | ((unsigned int)f2bf(b.w) << 16);
    return p;
}

__device__ __forceinline__ float4 ntload4(const float* p) {
    f32x4 v = __builtin_nontemporal_load(reinterpret_cast<const f32x4*>(p));
    float4 r; r.x = v[0]; r.y = v[1]; r.z = v[2]; r.w = v[3];
    return r;
}

#define GLOAD16(gp, lp) \
    __builtin_amdgcn_global_load_lds((const __attribute__((address_space(1))) void*)(gp), \
                                     (__attribute__((address_space(3))) void*)(lp), 16, 0, 0)

// ---------------- prep: MFMA gate (blocks 0..511) + W transpose (512..2559) ----------------
// (R15 verbatim — verified)
__global__ __launch_bounds__(256) void prep_kernel(const float* __restrict__ x,
        const float* __restrict__ gw, const float* __restrict__ gb,
        const float* __restrict__ ew,
        int* __restrict__ sel, int* __restrict__ nflag, int* __restrict__ flags,
        int* __restrict__ counts,
        unsigned short* __restrict__ xb, unsigned short* __restrict__ wt)
{
    __shared__ __align__(16) char smem[18688];
    int tid = threadIdx.x;

    if (blockIdx.x < 512) {
        // ---------------- gate via MFMA ----------------
        unsigned short* Ag = (unsigned short*)smem;           // [2][64*32] bf16
        unsigned short* Bg = (unsigned short*)(smem + 8192);
        int* h = (int*)(smem + 16384);
        if (tid < NEXP) h[tid] = 0;

        int t0 = blockIdx.x * 64;
        int lane = tid & 63;
        int w = tid >> 6;
        int lr = lane & 15, lg = lane >> 4;

        int rowS = tid >> 2;
        int koffS = (((tid & 3) ^ ((tid >> 3) & 3)) * 8);
        const float* xsrc = x + (size_t)(t0 + rowS) * DIM + koffS;
        const float* wsrc = gw + (size_t)rowS * DIM + koffS;
        unsigned short* xdst = xb ? xb + (size_t)(t0 + rowS) * DIM + koffS : nullptr;

        f32x4 acc[4];
#pragma unroll
        for (int n = 0; n < 4; n++)
#pragma unroll
            for (int c = 0; c < 4; c++) acc[n][c] = 0.f;

        float4 v0 = *reinterpret_cast<const float4*>(xsrc);
        float4 v1 = *reinterpret_cast<const float4*>(xsrc + 4);
        float4 v2 = *reinterpret_cast<const float4*>(wsrc);
        float4 v3 = *reinterpret_cast<const float4*>(wsrc + 4);
        {
            uint4 pa = pack8(v0, v1), pb = pack8(v2, v3);
            *reinterpret_cast<uint4*>(&Ag[tid * 8]) = pa;
            *reinterpret_cast<uint4*>(&Bg[tid * 8]) = pb;
            if (xdst) *reinterpret_cast<uint4*>(xdst) = pa;
        }
        __syncthreads();

        const char* Agc = (const char*)Ag;
        const char* Bgc = (const char*)Bg;
        int fko = (lg ^ ((lr >> 1) & 3)) * 16;

#pragma unroll 1
        for (int t = 0; t < 32; ++t) {
            if (t < 31) {
                int k0 = (t + 1) * 32;
                v0 = *reinterpret_cast<const float4*>(xsrc + k0);
                v1 = *reinterpret_cast<const float4*>(xsrc + k0 + 4);
                v2 = *reinterpret_cast<const float4*>(wsrc + k0);
                v3 = *reinterpret_cast<const float4*>(wsrc + k0 + 4);
            }
            int boff = (t & 1) * 4096;
            bf16x8 afr = *reinterpret_cast<const bf16x8*>(Agc + boff + ((w * 16 + lr) << 6) + fko);
#pragma unroll
            for (int n = 0; n < 4; n++) {
                bf16x8 bfr = *reinterpret_cast<const bf16x8*>(Bgc + boff + ((n * 16 + lr) << 6) + fko);
                acc[n] = __builtin_amdgcn_mfma_f32_16x16x32_bf16(afr, bfr, acc[n], 0, 0, 0);
            }
            if (t < 31) {
                uint4 pa = pack8(v0, v1), pb = pack8(v2, v3);
                int soff = ((t + 1) & 1) * 2048;
                *reinterpret_cast<uint4*>(&Ag[soff + tid * 8]) = pa;
                *reinterpret_cast<uint4*>(&Bg[soff + tid * 8]) = pb;
                if (xdst) *reinterpret_cast<uint4*>(xdst + (t + 1) * 32) = pa;
            }
            __syncthreads();
        }

        float gbv[4];
#pragma unroll
        for (int n = 0; n < 4; n++) gbv[n] = gb[n * 16 + lr];
#pragma unroll
        for (int i = 0; i < 4; i++) {
            float m1 = -1e30f, m2 = -1e30f; int e1 = 0;
#pragma unroll
            for (int n = 0; n < 4; n++) {
                float v = acc[n][i] + gbv[n];
                if (v > m1) { m2 = m1; m1 = v; e1 = n * 16 + lr; }
                else if (v > m2) m2 = v;
            }
#pragma unroll
            for (int d = 1; d < 16; d <<= 1) {
                float om1 = __shfl_xor(m1, d, 16);
                float om2 = __shfl_xor(m2, d, 16);
                int   oe1 = __shfl_xor(e1, d, 16);
                if (om1 > m1 || (om1 == m1 && oe1 < e1)) {
                    m2 = fmaxf(om2, m1); m1 = om1; e1 = oe1;
                } else {
                    m2 = fmaxf(m2, om1);
                }
            }
            if (lr == 0) {
                int t = t0 + w * 16 + lg * 4 + i;
                sel[t] = e1;
                atomicAdd(&h[e1], 1);
                if (m1 - m2 < 0.01f) {
                    int idx = atomicAdd(nflag, 1);
                    if (idx < 16384) flags[idx] = t;
                }
            }
        }
        __syncthreads();
        if (tid < NEXP && h[tid]) atomicAdd(&counts[tid], h[tid]);
    } else {
        // ---------------- W transpose, coarsened; ew reads nontemporal ----------------
        if (!wt) return;
        unsigned short* ts0 = (unsigned short*)smem;            // [64][72]
        unsigned short* ts1 = (unsigned short*)(smem + 9216);
        int lin = blockIdx.x - 512;        // 0..2047
        int e = lin >> 5;
        int d0 = ((lin >> 4) & 1) * 512;
        int o0 = (lin & 15) * 64;
        const float* src = ew + (size_t)e * (DIM * OUTD);
        unsigned short* dst = wt + (size_t)e * (DIM * OUTD);
        int og = tid & 7;
        int dl = tid >> 3;
        int dc = tid & 7;
        int ol = tid >> 3;

        float4 c0, c1, c2, c3;
        {
            const float* sr0 = &src[(size_t)(d0 + dl) * OUTD + o0 + og * 8];
            const float* sr1 = &src[(size_t)(d0 + dl + 32) * OUTD + o0 + og * 8];
            c0 = ntload4(sr0);
            c1 = ntload4(sr0 + 4);
            c2 = ntload4(sr1);
            c3 = ntload4(sr1 + 4);
        }
#pragma unroll
        for (int s = 0; s < 8; ++s) {
            float4 n0 = c0, n1 = c1, n2 = c2, n3 = c3;
            if (s < 7) {
                int dsn = d0 + (s + 1) * 64;
                const float* sr0 = &src[(size_t)(dsn + dl) * OUTD + o0 + og * 8];
                const float* sr1 = &src[(size_t)(dsn + dl + 32) * OUTD + o0 + og * 8];
                n0 = ntload4(sr0);
                n1 = ntload4(sr0 + 4);
                n2 = ntload4(sr1);
                n3 = ntload4(sr1 + 4);
            }
            unsigned short* tsb = (s & 1) ? ts1 : ts0;
#pragma unroll
            for (int half = 0; half < 2; ++half) {
                int dLoc = dl + 32 * half;
                float4 va = half ? c2 : c0;
                float4 vb = half ? c3 : c1;
                unsigned short b[8] = { f2bf(va.x), f2bf(va.y), f2bf(va.z), f2bf(va.w),
                                        f2bf(vb.x), f2bf(vb.y), f2bf(vb.z), f2bf(vb.w) };
                int dg = dLoc >> 3, dr = dLoc & 7;
#pragma unroll
                for (int k = 0; k < 8; k++) {
                    int o = og * 8 + k;
                    int key = (o & 7) ^ ((o >> 3) & 7);
                    tsb[o * 72 + ((dg ^ key) << 3) + dr] = b[k];
                }
            }
            __syncthreads();
            int ds0 = d0 + s * 64;
#pragma unroll
            for (int i = 0; i < 2; i++) {
                int o = ol + 32 * i;
                int key = (o & 7) ^ ((o >> 3) & 7);
                uint4 v = *reinterpret_cast<const uint4*>(&tsb[o * 72 + ((dc ^ key) << 3)]);
                *reinterpret_cast<uint4*>(&dst[(size_t)(o0 + o) * DIM + ds0 + dc * 8]) = v;
            }
            c0 = n0; c1 = n1; c2 = n2; c3 = n3;
        }
    }
}

// ---------------- fp64 re-resolution (R15 verbatim — verified) ----------------
__global__ __launch_bounds__(256) void gate_fix_kernel(const float* __restrict__ x,
        const float* __restrict__ gw, const float* __restrict__ gb,
        int* __restrict__ sel, const int* __restrict__ nflag, const int* __restrict__ flags,
        int* __restrict__ counts)
{
    __shared__ __align__(16) float xrow[4][DIM];
    int n = *nflag; if (n > 16384) n = 16384;
    int wv = threadIdx.x >> 6, lane = threadIdx.x & 63;
    int fi = blockIdx.x * 4 + wv;
    if (fi >= n) return;
    int t = flags[fi];

    const float4* xs4 = reinterpret_cast<const float4*>(x + (size_t)t * DIM);
    float4* xl4 = reinterpret_cast<float4*>(xrow[wv]);
#pragma unroll
    for (int i = 0; i < 4; i++)
        xl4[lane + i * 64] = xs4[lane + i * 64];

    const float4* wr4 = reinterpret_cast<const float4*>(gw + (size_t)lane * DIM);
    double a0 = 0, a1 = 0, a2 = 0, a3 = 0;
#pragma unroll 4
    for (int k = 0; k < DIM / 4; ++k) {
        float4 wv4 = wr4[k];
        float4 xv4 = xl4[k];
        a0 += (double)xv4.x * (double)wv4.x;
        a1 += (double)xv4.y * (double)wv4.y;
        a2 += (double)xv4.z * (double)wv4.z;
        a3 += (double)xv4.w * (double)wv4.w;
    }
    double m1 = ((a0 + a1) + (a2 + a3)) + (double)gb[lane];
    int e1 = lane;
#pragma unroll
    for (int d = 1; d < 64; d <<= 1) {
        double om1 = __shfl_xor(m1, d, 64);
        int   oe1  = __shfl_xor(e1, d, 64);
        if (om1 > m1 || (om1 == m1 && oe1 < e1)) { m1 = om1; e1 = oe1; }
    }
    if (lane == 0) {
        int eOld = sel[t];
        if (eOld != e1) {
            sel[t] = e1;
            atomicSub(&counts[eOld], 1);
            atomicAdd(&counts[e1], 1);
        }
    }
}

__global__ void sched_kernel(const int* __restrict__ counts, int* __restrict__ offsets,
                             int* __restrict__ schedE, int* __restrict__ schedR,
                             int* __restrict__ totalRB, int rowsShift)
{
    int e = threadIdx.x;
    int c = counts[e];
    int v = c;
#pragma unroll
    for (int d = 1; d < 64; d <<= 1) { int y = __shfl_up(v, d, 64); if (e >= d) v += y; }
    offsets[e] = v - c;
    if (e == 63) offsets[NEXP] = v;
    int rows = 1 << rowsShift;
    int nb = (c + rows - 1) >> rowsShift;
    int rbv = nb;
#pragma unroll
    for (int d = 1; d < 64; d <<= 1) { int y = __shfl_up(rbv, d, 64); if (e >= d) rbv += y; }
    int rbBase = rbv - nb;
    for (int i = 0; i < nb; i++) { schedE[rbBase + i] = e; schedR[rbBase + i] = i << rowsShift; }
    if (e == 63) *totalRB = rbv;
}

__global__ __launch_bounds__(256) void scatter_kernel(const int* __restrict__ sel,
        const int* __restrict__ offsets, int* __restrict__ cursor, int* __restrict__ perm)
{
    int t = blockIdx.x * 256 + threadIdx.x;
    int e = sel[t];
    int pos = offsets[e] + atomicAdd(&cursor[e], 1);
    perm[pos] = t;
}

// ---------------- grouped expert GEMM, 256x256x32, 16 waves, ring-4, 1 block/CU ----------------
// Geometry: 16 waves (1024 thr) x 64x64 output each -> acc[4][4] = 64 VGPR/lane
// (fits 128-cap honestly; R7 lesson). LDS ring-4: 4 bufs x (16K A + 16K B) = 128 KB.
// Single barrier/iter: stage(t+3) after barrier targets buf freed by it (ring>=3 rule).
// Counted vmcnt(4) = 2 tiles x 2 loads outstanding. Logical traffic: 768 -> 512 MB.
// decode: xcd=idx&7, cb=(idx>>3)&3, rb=(idx>>5)*8+xcd -> rb's 4 cb-blocks on one XCD.
__global__ __launch_bounds__(1024, 4) void moe_gemm10(
        const unsigned short* __restrict__ xb, const unsigned short* __restrict__ wt,
        const float* __restrict__ eb,
        const int* __restrict__ perm, const int* __restrict__ offsets,
        const int* __restrict__ counts, const int* __restrict__ schedE,
        const int* __restrict__ schedR, const int* __restrict__ totalRB,
        float* __restrict__ out)
{
    int idx = blockIdx.x;
    int xcd = idx & 7;
    int s = idx >> 3;
    int cb = s & 3;
    int rb = (s >> 2) * 8 + xcd;
    if (rb >= *totalRB) return;
    int e = schedE[rb], r0 = schedR[rb];
    int cnt = counts[e], base = offsets[e];

    __shared__ __align__(16) unsigned short As[32768];   // 4 bufs x 256 x 32 (64 KB)
    __shared__ __align__(16) unsigned short Bs[32768];   // 4 bufs x 256 x 32 (64 KB)

    int tid = threadIdx.x;
    int lane = tid & 63;
    int wv = tid >> 6;                  // 0..15
    int wr = wv >> 2, wc = wv & 3;      // 4x4 wave grid
    int lr = lane & 15, lg = lane >> 4;

    // staging: thread t -> A chunk t and B chunk t (1024 chunks = 256 rows x 4 kchunks)
    int rowS = tid >> 2;
    int koff = ((tid & 3) ^ ((tid >> 3) & 3)) * 8;   // key=(row>>1)&3, proven 0-conflict
    int rA = r0 + rowS;
    int tokA = (rA < cnt) ? perm[base + rA] : 0;
    const unsigned short* aSrc = xb + (size_t)tokA * DIM + koff;
    const unsigned short* bSrc = wt + ((size_t)e << 20)
                               + (size_t)(cb * 256 + rowS) * DIM + koff;

    unsigned short* AsQ = As + wv * 512;   // wave-uniform base (+lane*16B by HW)
    unsigned short* BsQ = Bs + wv * 512;

    f32x4 acc[4][4];
#pragma unroll
    for (int m = 0; m < 4; m++)
#pragma unroll
        for (int n = 0; n < 4; n++)
#pragma unroll
            for (int c = 0; c < 4; c++) acc[m][n][c] = 0.f;

    const char* Asc = (const char*)As;
    const char* Bsc = (const char*)Bs;
    int fko = (lg ^ ((lr >> 1) & 3)) * 16;

    auto stage = [&](int buf, int k0) {
        GLOAD16(aSrc + k0, AsQ + buf * 8192);
        GLOAD16(bSrc + k0, BsQ + buf * 8192);
    };
    auto compute = [&](int buf) {
        int boff = buf * 16384;  // bytes
        bf16x8 bfr[4];
#pragma unroll
        for (int n = 0; n < 4; n++) {
            int row = wc * 64 + n * 16 + lr;
            bfr[n] = *reinterpret_cast<const bf16x8*>(Bsc + boff + (row << 6) + fko);
        }
        __builtin_amdgcn_s_setprio(1);
#pragma unroll
        for (int m = 0; m < 4; m++) {
            int row = wr * 64 + m * 16 + lr;
            bf16x8 afr = *reinterpret_cast<const bf16x8*>(Asc + boff + (row << 6) + fko);
#pragma unroll
            for (int n = 0; n < 4; n++)
                acc[m][n] = __builtin_amdgcn_mfma_f32_16x16x32_bf16(afr, bfr[n], acc[m][n], 0, 0, 0);
        }
        __builtin_amdgcn_s_setprio(0);
    };

    // prologue: tiles 0,1,2 in flight (6 loads/thread)
    stage(0, 0);
    stage(1, 32);
    stage(2, 64);

#pragma unroll 1
    for (int t = 0; t < 29; ++t) {
        asm volatile("s_waitcnt vmcnt(4)" ::: "memory");   // tile t landed (own-wave)
        __builtin_amdgcn_s_barrier();                      // publish; frees buf (t-1)&3
        stage((t + 3) & 3, (t + 3) * 32);                  // tile t+3 -> freed buf
        compute(t & 3);
    }
    // tails: tiles 29,30,31 (no more staging)
    asm volatile("s_waitcnt vmcnt(4)" ::: "memory");
    __builtin_amdgcn_s_barrier();
    compute(29 & 3);
    asm volatile("s_waitcnt vmcnt(2)" ::: "memory");
    __builtin_amdgcn_s_barrier();
    compute(30 & 3);
    asm volatile("s_waitcnt vmcnt(0)" ::: "memory");
    __builtin_amdgcn_s_barrier();
    compute(31 & 3);

    // epilogue: C/D layout col = lane&15, row = (lane>>4)*4 + i; nt-stores
    float bias[4];
#pragma unroll
    for (int n = 0; n < 4; n++)
        bias[n] = eb[e * OUTD + cb * 256 + wc * 64 + n * 16 + lr];
#pragma unroll
    for (int m = 0; m < 4; m++) {
        int rowLoc = wr * 64 + m * 16 + lg * 4;
#pragma unroll
        for (int i2 = 0; i2 < 4; i2++) {
            int r = r0 + rowLoc + i2;
            if (r < cnt) {
                int tk = perm[base + r];
                float* op = out + (size_t)tk * OUTD + cb * 256 + wc * 64 + lr;
#pragma unroll
                for (int n = 0; n < 4; n++)
                    __builtin_nontemporal_store(acc[m][n][i2] + bias[n], op + n * 16);
            }
        }
    }
}

extern "C" void kernel_launch(void* const* d_in, const int* in_sizes, int n_in,
                              void* d_out, int out_size, void* d_ws, size_t ws_size,
                              hipStream_t stream)
{
    const float* x  = (const float*)d_in[0];
    const float* gw = (const float*)d_in[1];
    const float* gb = (const float*)d_in[2];
    const float* ew = (const float*)d_in[3];
    const float* eb = (const float*)d_in[4];
    float* out = (float*)d_out;

    char* ws = (char*)d_ws;
    int* counts  = (int*)(ws + 0);
    int* cursor  = (int*)(ws + 256);
    int* offsets = (int*)(ws + 512);
    int* totalRB = (int*)(ws + 1024);
    int* nflag   = (int*)(ws + 1028);
    int* schedE  = (int*)(ws + 2048);
    int* schedR  = (int*)(ws + 4096);
    int* flags   = (int*)(ws + 8192);      // 16384 ints
    int* sel     = (int*)(ws + 131072);
    int* perm    = (int*)(ws + 262144);

    const size_t WT_OFF   = (size_t)1 << 20;
    const size_t WT_BYTES = (size_t)NEXP * DIM * OUTD * 2;   // 128 MiB
    const size_t XB_OFF   = WT_OFF + WT_BYTES;
    const size_t XB_BYTES = (size_t)N_TOK * DIM * 2;         // 64 MiB
    int mode = (ws_size >= XB_OFF + XB_BYTES) ? 2 : 0;
    unsigned short* wt = (mode == 2) ? (unsigned short*)(ws + WT_OFF) : nullptr;
    unsigned short* xb = (mode == 2) ? (unsigned short*)(ws + XB_OFF) : nullptr;

    hipMemsetAsync(ws, 0, 2048, stream);

    prep_kernel<<<dim3(512 + ((mode == 2) ? 2048 : 0)), 256, 0, stream>>>(
        x, gw, gb, ew, sel, nflag, flags, counts, xb, wt);
    gate_fix_kernel<<<dim3(4096), 256, 0, stream>>>(x, gw, gb, sel, nflag, flags, counts);
    sched_kernel<<<dim3(1), 64, 0, stream>>>(counts, offsets, schedE, schedR, totalRB, 8);
    scatter_kernel<<<dim3(N_TOK / 256), 256, 0, stream>>>(sel, offsets, cursor, perm);

    moe_gemm10<<<dim3(1024), 1024, 0, stream>>>(xb, wt, eb, perm, offsets, counts,
                                                schedE, schedR, totalRB, out);
}

// Round 17
// 368.526 us; speedup vs baseline: 1.0211x; 1.0211x over previous
//
#include <hip/hip_runtime.h>
#include <hip/hip_bf16.h>

#define N_TOK 32768
#define DIM 1024
#define OUTD 1024
#define NEXP 64

typedef __attribute__((ext_vector_type(4))) float f32x4;
typedef __attribute__((ext_vector_type(8))) short bf16x8;

__device__ __forceinline__ unsigned short f2bf(float f) {
    unsigned int u = __builtin_bit_cast(unsigned int, f);
    u += 0x7FFFu + ((u >> 16) & 1u);   // RNE
    return (unsigned short)(u >> 16);
}

__device__ __forceinline__ uint4 pack8(float4 a, float4 b) {
    uint4 p;
    p.x = (unsigned int)f2bf(a.x) | ((unsigned int)f2bf(a.y) << 16);
    p.y = (unsigned int)f2bf(a.z) | ((unsigned int)f2bf(a.w) << 16);
    p.z = (unsigned int)f2bf(b.x) | ((unsigned int)f2bf(b.y) << 16);
    p.w = (unsigned int)f2bf(b.z) | ((unsigned int)f2bf(b.w) << 16);
    return p;
}

__device__ __forceinline__ float4 ntload4(const float* p) {
    f32x4 v = __builtin_nontemporal_load(reinterpret_cast<const f32x4*>(p));
    float4 r; r.x = v[0]; r.y = v[1]; r.z = v[2]; r.w = v[3];
    return r;
}

#define GLOAD16(gp, lp) \
    __builtin_amdgcn_global_load_lds((const __attribute__((address_space(1))) void*)(gp), \
                                     (__attribute__((address_space(3))) void*)(lp), 16, 0, 0)

// ---------------- prep: MFMA gate (blocks 0..511) + W transpose (512..2559) ----------------
// gate: R15 verbatim. transpose: depth-2 register prefetch (subtile s+2 issued before
// barrier(s)) -> ~2 phases of HBM-latency slack on the nt-load stream.
__global__ __launch_bounds__(256) void prep_kernel(const float* __restrict__ x,
        const float* __restrict__ gw, const float* __restrict__ gb,
        const float* __restrict__ ew,
        int* __restrict__ sel, int* __restrict__ nflag, int* __restrict__ flags,
        int* __restrict__ counts,
        unsigned short* __restrict__ xb, unsigned short* __restrict__ wt)
{
    __shared__ __align__(16) char smem[18688];
    int tid = threadIdx.x;

    if (blockIdx.x < 512) {
        // ---------------- gate via MFMA ----------------
        unsigned short* Ag = (unsigned short*)smem;           // [2][64*32] bf16
        unsigned short* Bg = (unsigned short*)(smem + 8192);
        int* h = (int*)(smem + 16384);
        if (tid < NEXP) h[tid] = 0;

        int t0 = blockIdx.x * 64;
        int lane = tid & 63;
        int w = tid >> 6;
        int lr = lane & 15, lg = lane >> 4;

        int rowS = tid >> 2;
        int koffS = (((tid & 3) ^ ((tid >> 3) & 3)) * 8);
        const float* xsrc = x + (size_t)(t0 + rowS) * DIM + koffS;
        const float* wsrc = gw + (size_t)rowS * DIM + koffS;
        unsigned short* xdst = xb ? xb + (size_t)(t0 + rowS) * DIM + koffS : nullptr;

        f32x4 acc[4];
#pragma unroll
        for (int n = 0; n < 4; n++)
#pragma unroll
            for (int c = 0; c < 4; c++) acc[n][c] = 0.f;

        float4 v0 = *reinterpret_cast<const float4*>(xsrc);
        float4 v1 = *reinterpret_cast<const float4*>(xsrc + 4);
        float4 v2 = *reinterpret_cast<const float4*>(wsrc);
        float4 v3 = *reinterpret_cast<const float4*>(wsrc + 4);
        {
            uint4 pa = pack8(v0, v1), pb = pack8(v2, v3);
            *reinterpret_cast<uint4*>(&Ag[tid * 8]) = pa;
            *reinterpret_cast<uint4*>(&Bg[tid * 8]) = pb;
            if (xdst) *reinterpret_cast<uint4*>(xdst) = pa;
        }
        __syncthreads();

        const char* Agc = (const char*)Ag;
        const char* Bgc = (const char*)Bg;
        int fko = (lg ^ ((lr >> 1) & 3)) * 16;

#pragma unroll 1
        for (int t = 0; t < 32; ++t) {
            if (t < 31) {
                int k0 = (t + 1) * 32;
                v0 = *reinterpret_cast<const float4*>(xsrc + k0);
                v1 = *reinterpret_cast<const float4*>(xsrc + k0 + 4);
                v2 = *reinterpret_cast<const float4*>(wsrc + k0);
                v3 = *reinterpret_cast<const float4*>(wsrc + k0 + 4);
            }
            int boff = (t & 1) * 4096;
            bf16x8 afr = *reinterpret_cast<const bf16x8*>(Agc + boff + ((w * 16 + lr) << 6) + fko);
#pragma unroll
            for (int n = 0; n < 4; n++) {
                bf16x8 bfr = *reinterpret_cast<const bf16x8*>(Bgc + boff + ((n * 16 + lr) << 6) + fko);
                acc[n] = __builtin_amdgcn_mfma_f32_16x16x32_bf16(afr, bfr, acc[n], 0, 0, 0);
            }
            if (t < 31) {
                uint4 pa = pack8(v0, v1), pb = pack8(v2, v3);
                int soff = ((t + 1) & 1) * 2048;
                *reinterpret_cast<uint4*>(&Ag[soff + tid * 8]) = pa;
                *reinterpret_cast<uint4*>(&Bg[soff + tid * 8]) = pb;
                if (xdst) *reinterpret_cast<uint4*>(xdst + (t + 1) * 32) = pa;
            }
            __syncthreads();
        }

        float gbv[4];
#pragma unroll
        for (int n = 0; n < 4; n++) gbv[n] = gb[n * 16 + lr];
#pragma unroll
        for (int i = 0; i < 4; i++) {
            float m1 = -1e30f, m2 = -1e30f; int e1 = 0;
#pragma unroll
            for (int n = 0; n < 4; n++) {
                float v = acc[n][i] + gbv[n];
                if (v > m1) { m2 = m1; m1 = v; e1 = n * 16 + lr; }
                else if (v > m2) m2 = v;
            }
#pragma unroll
            for (int d = 1; d < 16; d <<= 1) {
                float om1 = __shfl_xor(m1, d, 16);
                float om2 = __shfl_xor(m2, d, 16);
                int   oe1 = __shfl_xor(e1, d, 16);
                if (om1 > m1 || (om1 == m1 && oe1 < e1)) {
                    m2 = fmaxf(om2, m1); m1 = om1; e1 = oe1;
                } else {
                    m2 = fmaxf(m2, om1);
                }
            }
            if (lr == 0) {
                int t = t0 + w * 16 + lg * 4 + i;
                sel[t] = e1;
                atomicAdd(&h[e1], 1);
                if (m1 - m2 < 0.01f) {
                    int idx = atomicAdd(nflag, 1);
                    if (idx < 16384) flags[idx] = t;
                }
            }
        }
        __syncthreads();
        if (tid < NEXP && h[tid]) atomicAdd(&counts[tid], h[tid]);
    } else {
        // ---------------- W transpose, depth-2 prefetch; ew reads nontemporal ----------------
        if (!wt) return;
        unsigned short* ts0 = (unsigned short*)smem;            // [64][72]
        unsigned short* ts1 = (unsigned short*)(smem + 9216);
        int lin = blockIdx.x - 512;        // 0..2047
        int e = lin >> 5;
        int d0 = ((lin >> 4) & 1) * 512;
        int o0 = (lin & 15) * 64;
        const float* src = ew + (size_t)e * (DIM * OUTD);
        unsigned short* dst = wt + (size_t)e * (DIM * OUTD);
        int og = tid & 7;
        int dl = tid >> 3;
        int dc = tid & 7;
        int ol = tid >> 3;

        // prefetch subtiles 0 and 1
        float4 a0, a1, a2, a3, b0, b1, b2, b3;
        {
            const float* sr0 = &src[(size_t)(d0 + dl) * OUTD + o0 + og * 8];
            const float* sr1 = &src[(size_t)(d0 + dl + 32) * OUTD + o0 + og * 8];
            a0 = ntload4(sr0); a1 = ntload4(sr0 + 4);
            a2 = ntload4(sr1); a3 = ntload4(sr1 + 4);
            const float* sr2 = &src[(size_t)(d0 + 64 + dl) * OUTD + o0 + og * 8];
            const float* sr3 = &src[(size_t)(d0 + 64 + dl + 32) * OUTD + o0 + og * 8];
            b0 = ntload4(sr2); b1 = ntload4(sr2 + 4);
            b2 = ntload4(sr3); b3 = ntload4(sr3 + 4);
        }
#pragma unroll
        for (int s = 0; s < 8; ++s) {
            unsigned short* tsb = (s & 1) ? ts1 : ts0;
            // write phase: subtile s from regs a*
#pragma unroll
            for (int half = 0; half < 2; ++half) {
                int dLoc = dl + 32 * half;
                float4 va = half ? a2 : a0;
                float4 vb = half ? a3 : a1;
                unsigned short b[8] = { f2bf(va.x), f2bf(va.y), f2bf(va.z), f2bf(va.w),
                                        f2bf(vb.x), f2bf(vb.y), f2bf(vb.z), f2bf(vb.w) };
                int dg = dLoc >> 3, dr = dLoc & 7;
#pragma unroll
                for (int k = 0; k < 8; k++) {
                    int o = og * 8 + k;
                    int key = (o & 7) ^ ((o >> 3) & 7);
                    tsb[o * 72 + ((dg ^ key) << 3) + dr] = b[k];
                }
            }
            // prefetch subtile s+2 (lands during barrier + read(s) + write(s+1))
            float4 c0 = a0, c1 = a1, c2 = a2, c3 = a3;
            if (s < 6) {
                int dsn = d0 + (s + 2) * 64;
                const float* sr0 = &src[(size_t)(dsn + dl) * OUTD + o0 + og * 8];
                const float* sr1 = &src[(size_t)(dsn + dl + 32) * OUTD + o0 + og * 8];
                c0 = ntload4(sr0); c1 = ntload4(sr0 + 4);
                c2 = ntload4(sr1); c3 = ntload4(sr1 + 4);
            }
            __syncthreads();
            // read phase: write out transposed (coalesced 128B per o-row)
            int ds0 = d0 + s * 64;
#pragma unroll
            for (int i = 0; i < 2; i++) {
                int o = ol + 32 * i;
                int key = (o & 7) ^ ((o >> 3) & 7);
                uint4 v = *reinterpret_cast<const uint4*>(&tsb[o * 72 + ((dc ^ key) << 3)]);
                *reinterpret_cast<uint4*>(&dst[(size_t)(o0 + o) * DIM + ds0 + dc * 8]) = v;
            }
            a0 = b0; a1 = b1; a2 = b2; a3 = b3;
            b0 = c0; b1 = c1; b2 = c2; b3 = c3;
        }
    }
}

// ---------------- fp64 re-resolution (R15 verbatim — verified) ----------------
__global__ __launch_bounds__(256) void gate_fix_kernel(const float* __restrict__ x,
        const float* __restrict__ gw, const float* __restrict__ gb,
        int* __restrict__ sel, const int* __restrict__ nflag, const int* __restrict__ flags,
        int* __restrict__ counts)
{
    __shared__ __align__(16) float xrow[4][DIM];
    int n = *nflag; if (n > 16384) n = 16384;
    int wv = threadIdx.x >> 6, lane = threadIdx.x & 63;
    int fi = blockIdx.x * 4 + wv;
    if (fi >= n) return;
    int t = flags[fi];

    const float4* xs4 = reinterpret_cast<const float4*>(x + (size_t)t * DIM);
    float4* xl4 = reinterpret_cast<float4*>(xrow[wv]);
#pragma unroll
    for (int i = 0; i < 4; i++)
        xl4[lane + i * 64] = xs4[lane + i * 64];

    const float4* wr4 = reinterpret_cast<const float4*>(gw + (size_t)lane * DIM);
    double a0 = 0, a1 = 0, a2 = 0, a3 = 0;
#pragma unroll 4
    for (int k = 0; k < DIM / 4; ++k) {
        float4 wv4 = wr4[k];
        float4 xv4 = xl4[k];
        a0 += (double)xv4.x * (double)wv4.x;
        a1 += (double)xv4.y * (double)wv4.y;
        a2 += (double)xv4.z * (double)wv4.z;
        a3 += (double)xv4.w * (double)wv4.w;
    }
    double m1 = ((a0 + a1) + (a2 + a3)) + (double)gb[lane];
    int e1 = lane;
#pragma unroll
    for (int d = 1; d < 64; d <<= 1) {
        double om1 = __shfl_xor(m1, d, 64);
        int   oe1  = __shfl_xor(e1, d, 64);
        if (om1 > m1 || (om1 == m1 && oe1 < e1)) { m1 = om1; e1 = oe1; }
    }
    if (lane == 0) {
        int eOld = sel[t];
        if (eOld != e1) {
            sel[t] = e1;
            atomicSub(&counts[eOld], 1);
            atomicAdd(&counts[e1], 1);
        }
    }
}

__global__ void sched_kernel(const int* __restrict__ counts, int* __restrict__ offsets,
                             int* __restrict__ schedE, int* __restrict__ schedR,
                             int* __restrict__ totalRB, int rowsShift)
{
    int e = threadIdx.x;
    int c = counts[e];
    int v = c;
#pragma unroll
    for (int d = 1; d < 64; d <<= 1) { int y = __shfl_up(v, d, 64); if (e >= d) v += y; }
    offsets[e] = v - c;
    if (e == 63) offsets[NEXP] = v;
    int rows = 1 << rowsShift;
    int nb = (c + rows - 1) >> rowsShift;
    int rbv = nb;
#pragma unroll
    for (int d = 1; d < 64; d <<= 1) { int y = __shfl_up(rbv, d, 64); if (e >= d) rbv += y; }
    int rbBase = rbv - nb;
    for (int i = 0; i < nb; i++) { schedE[rbBase + i] = e; schedR[rbBase + i] = i << rowsShift; }
    if (e == 63) *totalRB = rbv;
}

__global__ __launch_bounds__(256) void scatter_kernel(const int* __restrict__ sel,
        const int* __restrict__ offsets, int* __restrict__ cursor, int* __restrict__ perm)
{
    int t = blockIdx.x * 256 + threadIdx.x;
    int e = sel[t];
    int pos = offsets[e] + atomicAdd(&cursor[e], 1);
    perm[pos] = t;
}

// ---------------- grouped expert GEMM, 256x128x32 bf16 MFMA, ring-3, 2 blocks/CU ----------------
// (R15 verbatim — verified best GEMM geometry; nt-stores for out)
__global__ __launch_bounds__(512, 4) void moe_gemm7(
        const unsigned short* __restrict__ xb, const unsigned short* __restrict__ wt,
        const float* __restrict__ eb,
        const int* __restrict__ perm, const int* __restrict__ offsets,
        const int* __restrict__ counts, const int* __restrict__ schedE,
        const int* __restrict__ schedR, const int* __restrict__ totalRB,
        float* __restrict__ out)
{
    int idx = blockIdx.x;
    int xcd = idx & 7;
    int s = idx >> 3;
    int cb = s & 7;
    int rb = (s >> 3) * 8 + xcd;
    if (rb >= *totalRB) return;
    int e = schedE[rb], r0 = schedR[rb];
    int cnt = counts[e], base = offsets[e];

    __shared__ __align__(16) unsigned short As[24576];   // 3 bufs x 256 x 32
    __shared__ __align__(16) unsigned short Bs[12288];   // 3 bufs x 128 x 32

    int tid = threadIdx.x;
    int lane = tid & 63;
    int wv = tid >> 6;
    int wr = wv >> 1, wc = wv & 1;
    int lr = lane & 15, lg = lane >> 4;

    int rowS = tid >> 2;
    int koff = ((tid & 3) ^ ((tid >> 3) & 3)) * 8;
    int rA1 = r0 + rowS, rA2 = r0 + 128 + rowS;
    int tokA1 = (rA1 < cnt) ? perm[base + rA1] : 0;
    int tokA2 = (rA2 < cnt) ? perm[base + rA2] : 0;

    const unsigned short* wte = wt + ((size_t)e << 20);
    const unsigned short* aSrc1 = xb + (size_t)tokA1 * DIM + koff;
    const unsigned short* aSrc2 = xb + (size_t)tokA2 * DIM + koff;
    const unsigned short* bSrc1 = wte + (size_t)(cb * 128 + rowS) * DIM + koff;

    unsigned short* AsQ0 = As + wv * 512;
    unsigned short* AsQ1 = As + 4096 + wv * 512;
    unsigned short* BsQ0 = Bs + wv * 512;

    f32x4 acc[4][4];
#pragma unroll
    for (int m = 0; m < 4; m++)
#pragma unroll
        for (int n = 0; n < 4; n++)
#pragma unroll
            for (int c = 0; c < 4; c++) acc[m][n][c] = 0.f;

    const char* Asc = (const char*)As;
    const char* Bsc = (const char*)Bs;
    int fko = (lg ^ ((lr >> 1) & 3)) * 16;

    auto stage = [&](int buf, int k0) {
        GLOAD16(aSrc1 + k0, AsQ0 + buf * 8192);
        GLOAD16(aSrc2 + k0, AsQ1 + buf * 8192);
        GLOAD16(bSrc1 + k0, BsQ0 + buf * 4096);
    };
    auto compute = [&](int buf) {
        int aoff = buf * 16384;
        int boff = buf * 8192;
        bf16x8 bfr[4];
#pragma unroll
        for (int n = 0; n < 4; n++) {
            int row = wc * 64 + n * 16 + lr;
            bfr[n] = *reinterpret_cast<const bf16x8*>(Bsc + boff + (row << 6) + fko);
        }
        __builtin_amdgcn_s_setprio(1);
#pragma unroll
        for (int m = 0; m < 4; m++) {
            int row = wr * 64 + m * 16 + lr;
            bf16x8 afr = *reinterpret_cast<const bf16x8*>(Asc + aoff + (row << 6) + fko);
#pragma unroll
            for (int n = 0; n < 4; n++)
                acc[m][n] = __builtin_amdgcn_mfma_f32_16x16x32_bf16(afr, bfr[n], acc[m][n], 0, 0, 0);
        }
        __builtin_amdgcn_s_setprio(0);
    };

    stage(0, 0);
    stage(1, 32);

    int cbuf = 0, sbuf = 2;
#pragma unroll 1
    for (int t = 0; t < 30; ++t) {
        asm volatile("s_waitcnt vmcnt(3)" ::: "memory");
        __builtin_amdgcn_s_barrier();
        stage(sbuf, (t + 2) * 32);
        compute(cbuf);
        cbuf = (cbuf == 2) ? 0 : cbuf + 1;
        sbuf = (sbuf == 2) ? 0 : sbuf + 1;
    }
    asm volatile("s_waitcnt vmcnt(3)" ::: "memory");
    __builtin_amdgcn_s_barrier();
    compute(cbuf);
    cbuf = (cbuf == 2) ? 0 : cbuf + 1;
    asm volatile("s_waitcnt vmcnt(0)" ::: "memory");
    __builtin_amdgcn_s_barrier();
    compute(cbuf);

    float bias[4];
#pragma unroll
    for (int n = 0; n < 4; n++)
        bias[n] = eb[e * OUTD + cb * 128 + wc * 64 + n * 16 + lr];
#pragma unroll
    for (int m = 0; m < 4; m++) {
        int rowLoc = wr * 64 + m * 16 + lg * 4;
#pragma unroll
        for (int i2 = 0; i2 < 4; i2++) {
            int r = r0 + rowLoc + i2;
            if (r < cnt) {
                int tk = perm[base + r];
                float* op = out + (size_t)tk * OUTD + cb * 128 + wc * 64 + lr;
#pragma unroll
                for (int n = 0; n < 4; n++)
                    __builtin_nontemporal_store(acc[m][n][i2] + bias[n], op + n * 16);
            }
        }
    }
}

extern "C" void kernel_launch(void* const* d_in, const int* in_sizes, int n_in,
                              void* d_out, int out_size, void* d_ws, size_t ws_size,
                              hipStream_t stream)
{
    const float* x  = (const float*)d_in[0];
    const float* gw = (const float*)d_in[1];
    const float* gb = (const float*)d_in[2];
    const float* ew = (const float*)d_in[3];
    const float* eb = (const float*)d_in[4];
    float* out = (float*)d_out;

    char* ws = (char*)d_ws;
    int* counts  = (int*)(ws + 0);
    int* cursor  = (int*)(ws + 256);
    int* offsets = (int*)(ws + 512);
    int* totalRB = (int*)(ws + 1024);
    int* nflag   = (int*)(ws + 1028);
    int* schedE  = (int*)(ws + 2048);
    int* schedR  = (int*)(ws + 4096);
    int* flags   = (int*)(ws + 8192);      // 16384 ints
    int* sel     = (int*)(ws + 131072);
    int* perm    = (int*)(ws + 262144);

    const size_t WT_OFF   = (size_t)1 << 20;
    const size_t WT_BYTES = (size_t)NEXP * DIM * OUTD * 2;   // 128 MiB
    const size_t XB_OFF   = WT_OFF + WT_BYTES;
    const size_t XB_BYTES = (size_t)N_TOK * DIM * 2;         // 64 MiB
    int mode = (ws_size >= XB_OFF + XB_BYTES) ? 2 : 0;
    unsigned short* wt = (mode == 2) ? (unsigned short*)(ws + WT_OFF) : nullptr;
    unsigned short* xb = (mode == 2) ? (unsigned short*)(ws + XB_OFF) : nullptr;

    hipMemsetAsync(ws, 0, 2048, stream);

    prep_kernel<<<dim3(512 + ((mode == 2) ? 2048 : 0)), 256, 0, stream>>>(
        x, gw, gb, ew, sel, nflag, flags, counts, xb, wt);
    gate_fix_kernel<<<dim3(4096), 256, 0, stream>>>(x, gw, gb, sel, nflag, flags, counts);
    sched_kernel<<<dim3(1), 64, 0, stream>>>(counts, offsets, schedE, schedR, totalRB, 8);
    scatter_kernel<<<dim3(N_TOK / 256), 256, 0, stream>>>(sel, offsets, cursor, perm);

    moe_gemm7<<<dim3(1536), 512, 0, stream>>>(xb, wt, eb, perm, offsets, counts,
                                              schedE, schedR, totalRB, out);
}

// Round 18
// 367.007 us; speedup vs baseline: 1.0253x; 1.0041x over previous
//
#include <hip/hip_runtime.h>
#include <hip/hip_bf16.h>

#define N_TOK 32768
#define DIM 1024
#define OUTD 1024
#define NEXP 64

typedef __attribute__((ext_vector_type(4))) float f32x4;
typedef __attribute__((ext_vector_type(8))) short bf16x8;

__device__ __forceinline__ unsigned short f2bf(float f) {
    unsigned int u = __builtin_bit_cast(unsigned int, f);
    u += 0x7FFFu + ((u >> 16) & 1u);   // RNE
    return (unsigned short)(u >> 16);
}

__device__ __forceinline__ uint4 pack8(float4 a, float4 b) {
    uint4 p;
    p.x = (unsigned int)f2bf(a.x) | ((unsigned int)f2bf(a.y) << 16);
    p.y = (unsigned int)f2bf(a.z) | ((unsigned int)f2bf(a.w) << 16);
    p.z = (unsigned int)f2bf(b.x) | ((unsigned int)f2bf(b.y) << 16);
    p.w = (unsigned int)f2bf(b.z) | ((unsigned int)f2bf(b.w) << 16);
    return p;
}

__device__ __forceinline__ float4 ntload4(const float* p) {
    f32x4 v = __builtin_nontemporal_load(reinterpret_cast<const f32x4*>(p));
    float4 r; r.x = v[0]; r.y = v[1]; r.z = v[2]; r.w = v[3];
    return r;
}

#define GLOAD16(gp, lp) \
    __builtin_amdgcn_global_load_lds((const __attribute__((address_space(1))) void*)(gp), \
                                     (__attribute__((address_space(3))) void*)(lp), 16, 0, 0)

// ---------------- prep: MFMA gate (blocks 0..511) + W transpose (512..2559) ----------------
// (R15 verbatim — measured best, 367 us total)
__global__ __launch_bounds__(256) void prep_kernel(const float* __restrict__ x,
        const float* __restrict__ gw, const float* __restrict__ gb,
        const float* __restrict__ ew,
        int* __restrict__ sel, int* __restrict__ nflag, int* __restrict__ flags,
        int* __restrict__ counts,
        unsigned short* __restrict__ xb, unsigned short* __restrict__ wt)
{
    __shared__ __align__(16) char smem[18688];
    int tid = threadIdx.x;

    if (blockIdx.x < 512) {
        // ---------------- gate via MFMA ----------------
        unsigned short* Ag = (unsigned short*)smem;           // [2][64*32] bf16
        unsigned short* Bg = (unsigned short*)(smem + 8192);
        int* h = (int*)(smem + 16384);
        if (tid < NEXP) h[tid] = 0;

        int t0 = blockIdx.x * 64;
        int lane = tid & 63;
        int w = tid >> 6;
        int lr = lane & 15, lg = lane >> 4;

        int rowS = tid >> 2;
        int koffS = (((tid & 3) ^ ((tid >> 3) & 3)) * 8);
        const float* xsrc = x + (size_t)(t0 + rowS) * DIM + koffS;
        const float* wsrc = gw + (size_t)rowS * DIM + koffS;
        unsigned short* xdst = xb ? xb + (size_t)(t0 + rowS) * DIM + koffS : nullptr;

        f32x4 acc[4];
#pragma unroll
        for (int n = 0; n < 4; n++)
#pragma unroll
            for (int c = 0; c < 4; c++) acc[n][c] = 0.f;

        float4 v0 = *reinterpret_cast<const float4*>(xsrc);
        float4 v1 = *reinterpret_cast<const float4*>(xsrc + 4);
        float4 v2 = *reinterpret_cast<const float4*>(wsrc);
        float4 v3 = *reinterpret_cast<const float4*>(wsrc + 4);
        {
            uint4 pa = pack8(v0, v1), pb = pack8(v2, v3);
            *reinterpret_cast<uint4*>(&Ag[tid * 8]) = pa;
            *reinterpret_cast<uint4*>(&Bg[tid * 8]) = pb;
            if (xdst) *reinterpret_cast<uint4*>(xdst) = pa;
        }
        __syncthreads();

        const char* Agc = (const char*)Ag;
        const char* Bgc = (const char*)Bg;
        int fko = (lg ^ ((lr >> 1) & 3)) * 16;

#pragma unroll 1
        for (int t = 0; t < 32; ++t) {
            if (t < 31) {
                int k0 = (t + 1) * 32;
                v0 = *reinterpret_cast<const float4*>(xsrc + k0);
                v1 = *reinterpret_cast<const float4*>(xsrc + k0 + 4);
                v2 = *reinterpret_cast<const float4*>(wsrc + k0);
                v3 = *reinterpret_cast<const float4*>(wsrc + k0 + 4);
            }
            int boff = (t & 1) * 4096;
            bf16x8 afr = *reinterpret_cast<const bf16x8*>(Agc + boff + ((w * 16 + lr) << 6) + fko);
#pragma unroll
            for (int n = 0; n < 4; n++) {
                bf16x8 bfr = *reinterpret_cast<const bf16x8*>(Bgc + boff + ((n * 16 + lr) << 6) + fko);
                acc[n] = __builtin_amdgcn_mfma_f32_16x16x32_bf16(afr, bfr, acc[n], 0, 0, 0);
            }
            if (t < 31) {
                uint4 pa = pack8(v0, v1), pb = pack8(v2, v3);
                int soff = ((t + 1) & 1) * 2048;
                *reinterpret_cast<uint4*>(&Ag[soff + tid * 8]) = pa;
                *reinterpret_cast<uint4*>(&Bg[soff + tid * 8]) = pb;
                if (xdst) *reinterpret_cast<uint4*>(xdst + (t + 1) * 32) = pa;
            }
            __syncthreads();
        }

        float gbv[4];
#pragma unroll
        for (int n = 0; n < 4; n++) gbv[n] = gb[n * 16 + lr];
#pragma unroll
        for (int i = 0; i < 4; i++) {
            float m1 = -1e30f, m2 = -1e30f; int e1 = 0;
#pragma unroll
            for (int n = 0; n < 4; n++) {
                float v = acc[n][i] + gbv[n];
                if (v > m1) { m2 = m1; m1 = v; e1 = n * 16 + lr; }
                else if (v > m2) m2 = v;
            }
#pragma unroll
            for (int d = 1; d < 16; d <<= 1) {
                float om1 = __shfl_xor(m1, d, 16);
                float om2 = __shfl_xor(m2, d, 16);
                int   oe1 = __shfl_xor(e1, d, 16);
                if (om1 > m1 || (om1 == m1 && oe1 < e1)) {
                    m2 = fmaxf(om2, m1); m1 = om1; e1 = oe1;
                } else {
                    m2 = fmaxf(m2, om1);
                }
            }
            if (lr == 0) {
                int t = t0 + w * 16 + lg * 4 + i;
                sel[t] = e1;
                atomicAdd(&h[e1], 1);
                if (m1 - m2 < 0.01f) {
                    int idx = atomicAdd(nflag, 1);
                    if (idx < 16384) flags[idx] = t;
                }
            }
        }
        __syncthreads();
        if (tid < NEXP && h[tid]) atomicAdd(&counts[tid], h[tid]);
    } else {
        // ---------------- W transpose, coarsened; ew reads nontemporal ----------------
        if (!wt) return;
        unsigned short* ts0 = (unsigned short*)smem;            // [64][72]
        unsigned short* ts1 = (unsigned short*)(smem + 9216);
        int lin = blockIdx.x - 512;        // 0..2047
        int e = lin >> 5;
        int d0 = ((lin >> 4) & 1) * 512;
        int o0 = (lin & 15) * 64;
        const float* src = ew + (size_t)e * (DIM * OUTD);
        unsigned short* dst = wt + (size_t)e * (DIM * OUTD);
        int og = tid & 7;
        int dl = tid >> 3;
        int dc = tid & 7;
        int ol = tid >> 3;

        float4 c0, c1, c2, c3;
        {
            const float* sr0 = &src[(size_t)(d0 + dl) * OUTD + o0 + og * 8];
            const float* sr1 = &src[(size_t)(d0 + dl + 32) * OUTD + o0 + og * 8];
            c0 = ntload4(sr0);
            c1 = ntload4(sr0 + 4);
            c2 = ntload4(sr1);
            c3 = ntload4(sr1 + 4);
        }
#pragma unroll
        for (int s = 0; s < 8; ++s) {
            float4 n0 = c0, n1 = c1, n2 = c2, n3 = c3;
            if (s < 7) {
                int dsn = d0 + (s + 1) * 64;
                const float* sr0 = &src[(size_t)(dsn + dl) * OUTD + o0 + og * 8];
                const float* sr1 = &src[(size_t)(dsn + dl + 32) * OUTD + o0 + og * 8];
                n0 = ntload4(sr0);
                n1 = ntload4(sr0 + 4);
                n2 = ntload4(sr1);
                n3 = ntload4(sr1 + 4);
            }
            unsigned short* tsb = (s & 1) ? ts1 : ts0;
#pragma unroll
            for (int half = 0; half < 2; ++half) {
                int dLoc = dl + 32 * half;
                float4 va = half ? c2 : c0;
                float4 vb = half ? c3 : c1;
                unsigned short b[8] = { f2bf(va.x), f2bf(va.y), f2bf(va.z), f2bf(va.w),
                                        f2bf(vb.x), f2bf(vb.y), f2bf(vb.z), f2bf(vb.w) };
                int dg = dLoc >> 3, dr = dLoc & 7;
#pragma unroll
                for (int k = 0; k < 8; k++) {
                    int o = og * 8 + k;
                    int key = (o & 7) ^ ((o >> 3) & 7);
                    tsb[o * 72 + ((dg ^ key) << 3) + dr] = b[k];
                }
            }
            __syncthreads();
            int ds0 = d0 + s * 64;
#pragma unroll
            for (int i = 0; i < 2; i++) {
                int o = ol + 32 * i;
                int key = (o & 7) ^ ((o >> 3) & 7);
                uint4 v = *reinterpret_cast<const uint4*>(&tsb[o * 72 + ((dc ^ key) << 3)]);
                *reinterpret_cast<uint4*>(&dst[(size_t)(o0 + o) * DIM + ds0 + dc * 8]) = v;
            }
            c0 = n0; c1 = n1; c2 = n2; c3 = n3;
        }
    }
}

// ---------------- fp64 re-resolution (R15 verbatim — verified) ----------------
__global__ __launch_bounds__(256) void gate_fix_kernel(const float* __restrict__ x,
        const float* __restrict__ gw, const float* __restrict__ gb,
        int* __restrict__ sel, const int* __restrict__ nflag, const int* __restrict__ flags,
        int* __restrict__ counts)
{
    __shared__ __align__(16) float xrow[4][DIM];
    int n = *nflag; if (n > 16384) n = 16384;
    int wv = threadIdx.x >> 6, lane = threadIdx.x & 63;
    int fi = blockIdx.x * 4 + wv;
    if (fi >= n) return;
    int t = flags[fi];

    const float4* xs4 = reinterpret_cast<const float4*>(x + (size_t)t * DIM);
    float4* xl4 = reinterpret_cast<float4*>(xrow[wv]);
#pragma unroll
    for (int i = 0; i < 4; i++)
        xl4[lane + i * 64] = xs4[lane + i * 64];

    const float4* wr4 = reinterpret_cast<const float4*>(gw + (size_t)lane * DIM);
    double a0 = 0, a1 = 0, a2 = 0, a3 = 0;
#pragma unroll 4
    for (int k = 0; k < DIM / 4; ++k) {
        float4 wv4 = wr4[k];
        float4 xv4 = xl4[k];
        a0 += (double)xv4.x * (double)wv4.x;
        a1 += (double)xv4.y * (double)wv4.y;
        a2 += (double)xv4.z * (double)wv4.z;
        a3 += (double)xv4.w * (double)wv4.w;
    }
    double m1 = ((a0 + a1) + (a2 + a3)) + (double)gb[lane];
    int e1 = lane;
#pragma unroll
    for (int d = 1; d < 64; d <<= 1) {
        double om1 = __shfl_xor(m1, d, 64);
        int   oe1  = __shfl_xor(e1, d, 64);
        if (om1 > m1 || (om1 == m1 && oe1 < e1)) { m1 = om1; e1 = oe1; }
    }
    if (lane == 0) {
        int eOld = sel[t];
        if (eOld != e1) {
            sel[t] = e1;
            atomicSub(&counts[eOld], 1);
            atomicAdd(&counts[e1], 1);
        }
    }
}

__global__ void sched_kernel(const int* __restrict__ counts, int* __restrict__ offsets,
                             int* __restrict__ schedE, int* __restrict__ schedR,
                             int* __restrict__ totalRB, int rowsShift)
{
    int e = threadIdx.x;
    int c = counts[e];
    int v = c;
#pragma unroll
    for (int d = 1; d < 64; d <<= 1) { int y = __shfl_up(v, d, 64); if (e >= d) v += y; }
    offsets[e] = v - c;
    if (e == 63) offsets[NEXP] = v;
    int rows = 1 << rowsShift;
    int nb = (c + rows - 1) >> rowsShift;
    int rbv = nb;
#pragma unroll
    for (int d = 1; d < 64; d <<= 1) { int y = __shfl_up(rbv, d, 64); if (e >= d) rbv += y; }
    int rbBase = rbv - nb;
    for (int i = 0; i < nb; i++) { schedE[rbBase + i] = e; schedR[rbBase + i] = i << rowsShift; }
    if (e == 63) *totalRB = rbv;
}

__global__ __launch_bounds__(256) void scatter_kernel(const int* __restrict__ sel,
        const int* __restrict__ offsets, int* __restrict__ cursor, int* __restrict__ perm)
{
    int t = blockIdx.x * 256 + threadIdx.x;
    int e = sel[t];
    int pos = offsets[e] + atomicAdd(&cursor[e], 1);
    perm[pos] = t;
}

// ---------------- grouped expert GEMM, 256x128x32 bf16 MFMA, ring-3, 2 blocks/CU ----------------
// (R15 verbatim — verified best GEMM geometry; nt-stores for out)
__global__ __launch_bounds__(512, 4) void moe_gemm7(
        const unsigned short* __restrict__ xb, const unsigned short* __restrict__ wt,
        const float* __restrict__ eb,
        const int* __restrict__ perm, const int* __restrict__ offsets,
        const int* __restrict__ counts, const int* __restrict__ schedE,
        const int* __restrict__ schedR, const int* __restrict__ totalRB,
        float* __restrict__ out)
{
    int idx = blockIdx.x;
    int xcd = idx & 7;
    int s = idx >> 3;
    int cb = s & 7;
    int rb = (s >> 3) * 8 + xcd;
    if (rb >= *totalRB) return;
    int e = schedE[rb], r0 = schedR[rb];
    int cnt = counts[e], base = offsets[e];

    __shared__ __align__(16) unsigned short As[24576];   // 3 bufs x 256 x 32
    __shared__ __align__(16) unsigned short Bs[12288];   // 3 bufs x 128 x 32

    int tid = threadIdx.x;
    int lane = tid & 63;
    int wv = tid >> 6;
    int wr = wv >> 1, wc = wv & 1;
    int lr = lane & 15, lg = lane >> 4;

    int rowS = tid >> 2;
    int koff = ((tid & 3) ^ ((tid >> 3) & 3)) * 8;
    int rA1 = r0 + rowS, rA2 = r0 + 128 + rowS;
    int tokA1 = (rA1 < cnt) ? perm[base + rA1] : 0;
    int tokA2 = (rA2 < cnt) ? perm[base + rA2] : 0;

    const unsigned short* wte = wt + ((size_t)e << 20);
    const unsigned short* aSrc1 = xb + (size_t)tokA1 * DIM + koff;
    const unsigned short* aSrc2 = xb + (size_t)tokA2 * DIM + koff;
    const unsigned short* bSrc1 = wte + (size_t)(cb * 128 + rowS) * DIM + koff;

    unsigned short* AsQ0 = As + wv * 512;
    unsigned short* AsQ1 = As + 4096 + wv * 512;
    unsigned short* BsQ0 = Bs + wv * 512;

    f32x4 acc[4][4];
#pragma unroll
    for (int m = 0; m < 4; m++)
#pragma unroll
        for (int n = 0; n < 4; n++)
#pragma unroll
            for (int c = 0; c < 4; c++) acc[m][n][c] = 0.f;

    const char* Asc = (const char*)As;
    const char* Bsc = (const char*)Bs;
    int fko = (lg ^ ((lr >> 1) & 3)) * 16;

    auto stage = [&](int buf, int k0) {
        GLOAD16(aSrc1 + k0, AsQ0 + buf * 8192);
        GLOAD16(aSrc2 + k0, AsQ1 + buf * 8192);
        GLOAD16(bSrc1 + k0, BsQ0 + buf * 4096);
    };
    auto compute = [&](int buf) {
        int aoff = buf * 16384;
        int boff = buf * 8192;
        bf16x8 bfr[4];
#pragma unroll
        for (int n = 0; n < 4; n++) {
            int row = wc * 64 + n * 16 + lr;
            bfr[n] = *reinterpret_cast<const bf16x8*>(Bsc + boff + (row << 6) + fko);
        }
        __builtin_amdgcn_s_setprio(1);
#pragma unroll
        for (int m = 0; m < 4; m++) {
            int row = wr * 64 + m * 16 + lr;
            bf16x8 afr = *reinterpret_cast<const bf16x8*>(Asc + aoff + (row << 6) + fko);
#pragma unroll
            for (int n = 0; n < 4; n++)
                acc[m][n] = __builtin_amdgcn_mfma_f32_16x16x32_bf16(afr, bfr[n], acc[m][n], 0, 0, 0);
        }
        __builtin_amdgcn_s_setprio(0);
    };

    stage(0, 0);
    stage(1, 32);

    int cbuf = 0, sbuf = 2;
#pragma unroll 1
    for (int t = 0; t < 30; ++t) {
        asm volatile("s_waitcnt vmcnt(3)" ::: "memory");
        __builtin_amdgcn_s_barrier();
        stage(sbuf, (t + 2) * 32);
        compute(cbuf);
        cbuf = (cbuf == 2) ? 0 : cbuf + 1;
        sbuf = (sbuf == 2) ? 0 : sbuf + 1;
    }
    asm volatile("s_waitcnt vmcnt(3)" ::: "memory");
    __builtin_amdgcn_s_barrier();
    compute(cbuf);
    cbuf = (cbuf == 2) ? 0 : cbuf + 1;
    asm volatile("s_waitcnt vmcnt(0)" ::: "memory");
    __builtin_amdgcn_s_barrier();
    compute(cbuf);

    float bias[4];
#pragma unroll
    for (int n = 0; n < 4; n++)
        bias[n] = eb[e * OUTD + cb * 128 + wc * 64 + n * 16 + lr];
#pragma unroll
    for (int m = 0; m < 4; m++) {
        int rowLoc = wr * 64 + m * 16 + lg * 4;
#pragma unroll
        for (int i2 = 0; i2 < 4; i2++) {
            int r = r0 + rowLoc + i2;
            if (r < cnt) {
                int tk = perm[base + r];
                float* op = out + (size_t)tk * OUTD + cb * 128 + wc * 64 + lr;
#pragma unroll
                for (int n = 0; n < 4; n++)
                    __builtin_nontemporal_store(acc[m][n][i2] + bias[n], op + n * 16);
            }
        }
    }
}

extern "C" void kernel_launch(void* const* d_in, const int* in_sizes, int n_in,
                              void* d_out, int out_size, void* d_ws, size_t ws_size,
                              hipStream_t stream)
{
    const float* x  = (const float*)d_in[0];
    const float* gw = (const float*)d_in[1];
    const float* gb = (const float*)d_in[2];
    const float* ew = (const float*)d_in[3];
    const float* eb = (const float*)d_in[4];
    float* out = (float*)d_out;

    char* ws = (char*)d_ws;
    int* counts  = (int*)(ws + 0);
    int* cursor  = (int*)(ws + 256);
    int* offsets = (int*)(ws + 512);
    int* totalRB = (int*)(ws + 1024);
    int* nflag   = (int*)(ws + 1028);
    int* schedE  = (int*)(ws + 2048);
    int* schedR  = (int*)(ws + 4096);
    int* flags   = (int*)(ws + 8192);      // 16384 ints
    int* sel     = (int*)(ws + 131072);
    int* perm    = (int*)(ws + 262144);

    const size_t WT_OFF   = (size_t)1 << 20;
    const size_t WT_BYTES = (size_t)NEXP * DIM * OUTD * 2;   // 128 MiB
    const size_t XB_OFF   = WT_OFF + WT_BYTES;
    const size_t XB_BYTES = (size_t)N_TOK * DIM * 2;         // 64 MiB
    int mode = (ws_size >= XB_OFF + XB_BYTES) ? 2 : 0;
    unsigned short* wt = (mode == 2) ? (unsigned short*)(ws + WT_OFF) : nullptr;
    unsigned short* xb = (mode == 2) ? (unsigned short*)(ws + XB_OFF) : nullptr;

    hipMemsetAsync(ws, 0, 2048, stream);

    prep_kernel<<<dim3(512 + ((mode == 2) ? 2048 : 0)), 256, 0, stream>>>(
        x, gw, gb, ew, sel, nflag, flags, counts, xb, wt);
    gate_fix_kernel<<<dim3(4096), 256, 0, stream>>>(x, gw, gb, sel, nflag, flags, counts);
    sched_kernel<<<dim3(1), 64, 0, stream>>>(counts, offsets, schedE, schedR, totalRB, 8);
    scatter_kernel<<<dim3(N_TOK / 256), 256, 0, stream>>>(sel, offsets, cursor, perm);

    moe_gemm7<<<dim3(1536), 512, 0, stream>>>(xb, wt, eb, perm, offsets, counts,
                                              schedE, schedR, totalRB, out);
}